// Round 5
// baseline (530.658 us; speedup 1.0000x reference)
//
#include <hip/hip_runtime.h>
#include <math.h>

#define KS 48
#define TLEN 512
#define BN 1024
#define START_S 46
#define STOP_S 47
#define NEGV -10000.0f
#define PF 8   // emission prefetch depth

typedef float v2f __attribute__((ext_vector_type(2)));

__device__ __forceinline__ float bcast_lane0(float v) {
    return __builtin_bit_cast(float, __builtin_amdgcn_readfirstlane(__builtin_bit_cast(int, v)));
}

// wave argmax, first-index tie-break (matches jnp.argmax; validated rounds 1-7)
__device__ __forceinline__ void wargmax(float& bv, int& bi) {
    #pragma unroll
    for (int off = 32; off; off >>= 1) {
        float ov = __shfl_xor(bv, off, 64);
        int   oi = __shfl_xor(bi, off, 64);
        if (ov > bv || (ov == bv && oi < bi)) { bv = ov; bi = oi; }
    }
}

// grid = 1024, 1-wave blocks. ROUND-12 CHANGE (exposed-latency theory):
// R1 (no DS in scan) and R2 (+125 VALU) both left dur unchanged -> the scan is
// bound by EXPOSED per-step chain latency with 1 wave/SIMD idling through it
// (occupancy 16.6% = 1 wave/SIMD for 2/3 of the run). Fix: fuse forward and
// viterbi for the SAME sequence into ONE wave. Both consume the same emission
// row at the same t (one load feeds both -> feats fetched once), and the two
// independent chains fill each other's stall windows. Arithmetic bodies are
// verbatim R3 (absmax 0.0 for 5 rounds). bp ring = 128 slots so group flushes
// never collide with the t+1-offset chunking.
__global__ __launch_bounds__(64) void crf13(
    const float* __restrict__ feats,   // [B, T, K]
    const float* __restrict__ trans,   // [K, K]  trans[next, prev]
    const int*   __restrict__ tags,    // [B, T]
    float*       __restrict__ out,     // [B] nll | [B] path_score | [B*T] paths
    unsigned char* __restrict__ bp_g)  // [B, T, K] backpointer bytes (groups 0-6)
{
    const int lane = threadIdx.x;
    const bool act = lane < KS;

    __shared__ float xf[64];                       // fwd exchange buffer
    __shared__ float xv[64];                       // vit exchange buffer
    __shared__ __align__(16) unsigned char seg[128 * KS];  // 6 KB 2-group bp ring
    __shared__ unsigned char path_sh[TLEN];

    const int b = blockIdx.x;
    const float* fb = feats + (size_t)b * TLEN * KS;
    const int*   tb = tags + (size_t)b * TLEN;
    unsigned char* bpb = bp_g + (size_t)b * TLEN * KS;

    // ---- tables (masked trans row per next=lane; Erow = exp for fwd) ----
    float Erow[KS], Trow[KS];
    {
        const float* tr = trans + (act ? lane : 0) * KS;
        #pragma unroll
        for (int p = 0; p < KS; ++p) {
            float tv = act ? tr[p] : NEGV;
            if (lane == START_S) tv = NEGV;
            if (p == STOP_S)     tv = NEGV;
            Trow[p] = tv;
            Erow[p] = __expf(tv);
        }
    }
    float tstart = act ? trans[lane * KS + START_S] : NEGV;
    if (lane == START_S) tstart = NEGV;

    // ---- forward state + step (R3 bits, xf buffer) ----
    float alpha;
    auto fstep = [&](float emv) {
        float s  = bcast_lane0(alpha);       // lane-0 alpha finite: valid shift
        float ue = __expf(alpha - s);        // -inf lanes -> 0
        xf[lane] = ue;                       // same-wave in-order LDS: no barrier
        const float4* uu = (const float4*)xf;
        v2f acc0 = {0.f, 0.f}, acc1 = {0.f, 0.f};
        #pragma unroll
        for (int g = 0; g < KS / 4; ++g) {
            float4 u = uu[g];
            v2f ua = {u.x, u.y}, ub = {u.z, u.w};
            v2f ea = {Erow[4 * g + 0], Erow[4 * g + 1]};
            v2f eb = {Erow[4 * g + 2], Erow[4 * g + 3]};
            acc0 = __builtin_elementwise_fma(ua, ea, acc0);
            acc1 = __builtin_elementwise_fma(ub, eb, acc1);
        }
        alpha = emv + s + __logf((acc0.x + acc0.y) + (acc1.x + acc1.y));
    };

    // ---- viterbi state + step (R3 bits: argmax tree, 128-slot ring) ----
    float vit = (lane == START_S) ? 0.0f : NEGV;
    auto vstep = [&](float emv, int t) {
        xv[lane] = vit;                      // in-order LDS, no barrier
        const float4* ww = (const float4*)xv;
        float bs[12]; int ib[12];
        #pragma unroll
        for (int g = 0; g < KS / 4; ++g) {
            float4 w = ww[g];
            v2f wa = {w.x, w.y}, wb = {w.z, w.w};
            v2f ta = {Trow[4 * g + 0], Trow[4 * g + 1]};
            v2f tc = {Trow[4 * g + 2], Trow[4 * g + 3]};
            v2f sa = wa + ta;
            v2f sb = wb + tc;
            float m01 = fmaxf(sa.x, sa.y); int i01 = (sa.y > sa.x) ? 4 * g + 1 : 4 * g + 0;
            float m23 = fmaxf(sb.x, sb.y); int i23 = (sb.y > sb.x) ? 4 * g + 3 : 4 * g + 2;
            bs[g] = fmaxf(m01, m23);       ib[g] = (m23 > m01) ? i23 : i01;
        }
        #pragma unroll
        for (int st = 0; st < 6; ++st) {
            float a = bs[2 * st], c2 = bs[2 * st + 1];
            int ia = ib[2 * st], ic = ib[2 * st + 1];
            bs[st] = fmaxf(a, c2); ib[st] = (c2 > a) ? ic : ia;
        }
        #pragma unroll
        for (int st = 0; st < 3; ++st) {
            float a = bs[2 * st], c2 = bs[2 * st + 1];
            int ia = ib[2 * st], ic = ib[2 * st + 1];
            bs[st] = fmaxf(a, c2); ib[st] = (c2 > a) ? ic : ia;
        }
        float best = fmaxf(bs[0], bs[1]);
        int   bi   = (bs[1] > bs[0]) ? ib[1] : ib[0];
        bi   = (bs[2] > best) ? ib[2] : bi;
        best = fmaxf(best, bs[2]);
        if (act) seg[(t & 127) * KS + lane] = (unsigned char)bi;  // LDS ring
        vit = best + emv;
    };

    // ---- t=0 peel: one row-0 load feeds both scans ----
    float r0 = act ? fb[lane] : 0.0f;
    alpha = (act ? r0 : -INFINITY) + tstart;
    vstep(r0, 0);

    // ---- main loop t=1..511: shared em prefetch, interleaved steps ----
    // em[j] holds row 1+c*8+j. Inactive lanes get 0.0f (proven harmless for
    // fwd: junk alpha stays finite-moderate, terminal masks via tstop=NEGV
    // and exp underflow -> identical logZ bits).
    float em[PF];
    #pragma unroll
    for (int j = 0; j < PF; ++j)
        em[j] = act ? fb[(1 + j) * KS + lane] : 0.0f;
    for (int c = 0; c < 63; ++c) {
        const int t0 = 1 + c * PF;
        float em_n[PF];
        #pragma unroll
        for (int j = 0; j < PF; ++j) {
            int tf = t0 + PF + j;
            em_n[j] = (act && tf < TLEN) ? fb[tf * KS + lane] : 0.0f;
        }
        #pragma unroll
        for (int j = 0; j < PF; ++j) {
            vstep(em[j], t0 + j);            // independent chains: compiler
            fstep(em[j]);                    // interleaves freely (no fences)
        }
        // flush completed bp group g=c>>3 (chunk c=8g+7 ends at t=64g+64,
        // which lands in the OTHER ring half -> no overwrite hazard).
        if ((c & 7) == 7 && c < 56) {
            const int g = c >> 3;
            const float4* s4 = (const float4*)(seg + (g & 1) * 64 * KS);
            float4* d4 = (float4*)(bpb + (size_t)g * 64 * KS);
            #pragma unroll
            for (int i = 0; i < 3; ++i)
                d4[lane + 64 * i] = s4[lane + 64 * i];   // 3 KB burst
        }
        #pragma unroll
        for (int j = 0; j < PF; ++j) em[j] = em_n[j];
    }
    #pragma unroll
    for (int j = 0; j < 7; ++j) {            // tail t=505..511
        vstep(em[j], 505 + j);
        fstep(em[j]);
    }

    // drain flush stores before backtrace re-reads
    asm volatile("s_waitcnt vmcnt(0)" ::: "memory");

    // ---- forward terminal: logZ, gold score, nll ----
    float tstop = act ? trans[STOP_S * KS + lane] : NEGV;
    if (lane == STOP_S) tstop = NEGV;
    {
        float z = alpha + tstop;
        float mz = z;
        #pragma unroll
        for (int off = 32; off; off >>= 1)
            mz = fmaxf(mz, __shfl_xor(mz, off, 64));
        float se = __expf(z - mz);
        #pragma unroll
        for (int off = 32; off; off >>= 1)
            se += __shfl_xor(se, off, 64);
        float logZ = mz + __logf(se);

        float g = 0.0f;
        for (int t = lane; t < TLEN; t += 64) {
            int tg = tb[t];
            int pg = (t == 0) ? START_S : tb[t - 1];
            g += fb[t * KS + tg] + trans[tg * KS + pg];
        }
        #pragma unroll
        for (int off = 32; off; off >>= 1)
            g += __shfl_xor(g, off, 64);
        g += trans[STOP_S * KS + tb[TLEN - 1]];

        if (lane == 0) out[b] = logZ - g;
    }

    // ---- viterbi terminal + backtrace ----
    float term = act ? (vit + tstop) : -3.0e38f;
    float bv = term;
    int   bidx = act ? lane : 9999;
    wargmax(bv, bidx);
    if (lane == 0) out[BN + b] = bv;

    // group 7 (t=448..511) is resident in ring slots 64..127: chase it first.
    int tag = bidx;
    for (int t = 63; t >= 0; --t) {
        path_sh[448 + t] = (unsigned char)tag;
        tag = seg[(64 + t) * KS + tag];
    }
    for (int s = 6; s >= 0; --s) {
        float4 tmp[3];
        const float4* src = (const float4*)(bpb + (size_t)s * 64 * KS);
        #pragma unroll
        for (int i = 0; i < 3; ++i)
            tmp[i] = src[lane + 64 * i];
        // same-wave in-order DS: prior chase reads precede these writes
        float4* dst = (float4*)seg;              // lower half (slots 0..63)
        #pragma unroll
        for (int i = 0; i < 3; ++i)
            dst[lane + 64 * i] = tmp[i];
        for (int t = 63; t >= 0; --t) {
            path_sh[s * 64 + t] = (unsigned char)tag;  // tag at time s*64+t
            tag = seg[t * KS + tag];                   // -> tag at t-1
        }
    }
    __syncthreads();   // single wave: drains LDS before the read-back
    float* pout = out + 2 * BN + (size_t)b * TLEN;
    for (int t = lane; t < TLEN; t += 64)
        pout[t] = (float)path_sh[t];
}

extern "C" void kernel_launch(void* const* d_in, const int* in_sizes, int n_in,
                              void* d_out, int out_size, void* d_ws, size_t ws_size,
                              hipStream_t stream) {
    const float* feats = (const float*)d_in[0];
    const float* trans = (const float*)d_in[1];
    const int*   tags  = (const int*)d_in[2];
    float*       out   = (float*)d_out;
    (void)in_sizes; (void)n_in; (void)out_size; (void)ws_size;

    // workspace use: groups 0..6 of [B, T, K] bp bytes ≈ 22 MB (ws ≥ 100 MB)
    crf13<<<dim3(BN), dim3(64), 0, stream>>>(feats, trans, tags, out,
                                             (unsigned char*)d_ws);
}